// Round 12
// baseline (735.767 us; speedup 1.0000x reference)
//
#include <hip/hip_runtime.h>
#include <stdint.h>

// ---------- types / helpers ----------
typedef __attribute__((ext_vector_type(8))) short bf16x8;   // 8 bf16 in 4 VGPRs
typedef __attribute__((ext_vector_type(4))) float f32x4;

static __device__ __forceinline__ short f2bf(float f) {
  uint32_t u = __builtin_bit_cast(uint32_t, f);
  u += 0x7fffu + ((u >> 16) & 1u);          // round-to-nearest-even
  return (short)(u >> 16);
}

static __device__ __forceinline__ void gload_lds16(const void* g, void* l) {
  __builtin_amdgcn_global_load_lds((const __attribute__((address_space(1))) void*)g,
                                   (__attribute__((address_space(3))) void*)l, 16, 0, 0);
}

#define GFENCE asm volatile("" ::: "memory")

// ---------- x transpose: (B,C,T,H,W) f32 -> xb[n][c] bf16, n = b*16384 + p ----------
__global__ __launch_bounds__(256) void transpose_x_k(const float* __restrict__ x,
                                                     short* __restrict__ xb) {
  __shared__ float t[64][65];
  const int pt = blockIdx.x, ct = blockIdx.y, b = blockIdx.z;
  const int tid = threadIdx.x;
#pragma unroll
  for (int i = 0; i < 16; i++) {
    int cc = i * 4 + (tid >> 6);
    int pp = tid & 63;
    t[cc][pp] = x[(size_t)(b * 512 + ct * 64 + cc) * 16384 + pt * 64 + pp];
  }
  __syncthreads();
#pragma unroll
  for (int i = 0; i < 2; i++) {
    int seg = i * 256 + tid;
    int pw = seg >> 3, c8 = seg & 7;
    short tmp[8];
#pragma unroll
    for (int k = 0; k < 8; k++) tmp[k] = f2bf(t[c8 * 8 + k][pw]);
    *(uint4*)&xb[(size_t)(b * 16384 + pt * 64 + pw) * 512 + ct * 64 + c8 * 8] =
        *(const uint4*)tmp;
  }
}

// ---------- weight transpose: 12x (512x512 f32 [k][n]) -> bf16 [n][k], per-dst ld ----------
struct WPtrs {
  const float* src[12];
  short* dst[12];
  int ld[12];
};

__global__ __launch_bounds__(256) void transpose_w_k(WPtrs P) {
  __shared__ float t[64][65];
  const int kt = blockIdx.x, nt = blockIdx.y, z = blockIdx.z;
  const float* src = P.src[z];
  short* dst = P.dst[z];
  const int ld = P.ld[z];
  const int tid = threadIdx.x;
#pragma unroll
  for (int i = 0; i < 16; i++) {
    int kk = i * 4 + (tid >> 6);
    int nn = tid & 63;
    t[kk][nn] = src[(kt * 64 + kk) * 512 + nt * 64 + nn];
  }
  __syncthreads();
#pragma unroll
  for (int i = 0; i < 2; i++) {
    int seg = i * 256 + tid;
    int nn = seg >> 3, k8 = seg & 7;
    short tmp[8];
#pragma unroll
    for (int k = 0; k < 8; k++) tmp[k] = f2bf(t[k8 * 8 + k][nn]);
    *(uint4*)&dst[(size_t)(nt * 64 + nn) * ld + kt * 64 + k8 * 8] = *(const uint4*)tmp;
  }
}

__global__ void bsum_k(const float* a, const float* b, const float* c, float* o) {
  int i = blockIdx.x * 256 + threadIdx.x;
  if (i < 512) o[i] = a[i] + b[i] + c[i];
}

// ---------- 256x256 GEMM, 16 waves (1024 thr), 2 phases/K-tile ----------
// Same LDS layout/swizzle/stage-order as the proven round-4 kernel; wave now owns a
// 64x64 quadrant (wr=wave>>2, wc=wave&3), acc 4x4 f32x4 = 64 VGPR (fits 128 cap).
// LDS: 2 bufs x {ALO,AHI,BLO,BHI} x 16 KB. Stage = 1 gload_lds/thread (1024 thr
// cover one 16 KB half exactly; dest wave*1024 linear; global chunk pre-swizzled).
// Phase: [vmcnt][barrier][read B,A (8 b128)][2 stages][16 MFMA].
// PH0(t): reads kh0, stages AHI/BHI(t+1). PH1(t): reads kh1, stages ALO/BLO(t+2).
// Ledger (1 load per stage call): prologue 6; steady vmcnt(4)/vmcnt(4);
// tail: NT-2 4/4 (PH1 no stage), NT-1 2/0. WAR safe: each stage's target half was
// last read one barrier earlier (reads retire pre-MFMA, pre-next-barrier).
// MODE 0: D bf16 [M][ldd].  MODE 1: D f32 out (B,C,THW) = v + bsum[c].
#define READ_AB(b, kh)                                                         \
  do {                                                                         \
    _Pragma("unroll") for (int ni = 0; ni < 4; ++ni) bfr[ni] =                 \
        *(const bf16x8*)(smem + ((b) * 4 + 2 + (kh)) * 16384 + boff +          \
                         ni * 1024);                                           \
    _Pragma("unroll") for (int mi = 0; mi < 4; ++mi) af[mi] =                  \
        *(const bf16x8*)(smem + ((b) * 4 + (kh)) * 16384 + aoff + mi * 1024);  \
  } while (0)

#define MFMA16X                                                                \
  do {                                                                         \
    __builtin_amdgcn_s_setprio(1);                                             \
    _Pragma("unroll") for (int mi = 0; mi < 4; ++mi)                           \
        _Pragma("unroll") for (int ni = 0; ni < 4; ++ni) acc[mi][ni] =         \
            __builtin_amdgcn_mfma_f32_16x16x32_bf16(af[mi], bfr[ni],           \
                                                    acc[mi][ni], 0, 0, 0);     \
    __builtin_amdgcn_s_setprio(0);                                             \
    GFENCE;                                                                    \
  } while (0)

#define PH(b, kh, W, SA, SB)                                                   \
  do {                                                                         \
    asm volatile("s_waitcnt vmcnt(" W ")" ::: "memory");                       \
    __builtin_amdgcn_s_barrier();                                              \
    GFENCE;                                                                    \
    READ_AB(b, kh);                                                            \
    SA;                                                                        \
    SB;                                                                        \
    GFENCE;                                                                    \
    MFMA16X;                                                                   \
  } while (0)

template <int MODE>
__global__ __launch_bounds__(1024) void gemm256_k(const short* __restrict__ A,
                                                  int lda,
                                                  const short* __restrict__ B,
                                                  int ldb, void* __restrict__ Dp,
                                                  int K, int ldd,
                                                  const float* __restrict__ bsum,
                                                  int GN) {
  extern __shared__ char smem[];
  const int tid = threadIdx.x;
  const int lane = tid & 63, wave = tid >> 6;   // 16 waves
  const int wr = wave >> 2, wc = wave & 3;      // 4x4 quadrant grid
  const int r4 = lane & 15, kl = lane >> 4;

  // bijective XCD swizzle (gridDim.x % 8 == 0 for all our grids)
  int bid = blockIdx.x;
  const int cpx = gridDim.x >> 3;
  bid = (bid & 7) * cpx + (bid >> 3);
  int bm, bn;
  if constexpr (MODE == 0) {
    bn = bid % GN;
    bm = bid / GN;
  } else {
    bm = bid & 1;
    bn = bid >> 1;
  }

  const int NT = K >> 6;

  // staging: thread -> (row = tid>>2, chunk slot = tid&3); global chunk swizzled
  const int srow = tid >> 2;                       // 0..255
  const int schk = (tid & 3) ^ ((tid >> 4) & 3);   // involution per 16-row subtile
  const short* gA0 = A + (size_t)(bm * 256 + srow) * lda + schk * 8;
  const short* gB0 = B + (size_t)(bn * 256 + srow) * ldb + schk * 8;

  auto stage = [&](int tt, int x) {  // x: 0 ALO, 1 AHI, 2 BLO, 3 BHI
    const short* g = (x < 2) ? gA0 : gB0;
    const size_t koff = (size_t)tt * 64 + (x & 1) * 32;
    gload_lds16(g + koff, smem + (((tt & 1) * 4 + x) * 16384) + wave * 1024);
  };

  // fragment read offsets (swizzled: kl ^= r4>>2 within the 1 KiB subtile)
  const int kls = kl ^ (r4 >> 2);
  const int aoff = wr * 4096 + r4 * 64 + kls * 16;
  const int boff = wc * 4096 + r4 * 64 + kls * 16;

  f32x4 acc[4][4];
#pragma unroll
  for (int i = 0; i < 4; ++i)
#pragma unroll
    for (int j = 0; j < 4; ++j) acc[i][j] = (f32x4){0.f, 0.f, 0.f, 0.f};
  bf16x8 af[4], bfr[4];

  // prologue: ALO0 BLO0 AHI0 BHI0 ALO1 BLO1 (6 loads/thread in flight)
  stage(0, 0);
  stage(0, 2);
  stage(0, 1);
  stage(0, 3);
  stage(1, 0);
  stage(1, 2);

  int t = 0;
  for (; t < NT - 2; ++t) {
    const int b = t & 1;
    PH(b, 0, "4", stage(t + 1, 1), stage(t + 1, 3));
    PH(b, 1, "4", stage(t + 2, 0), stage(t + 2, 2));
  }
  {
    const int b = t & 1;  // t == NT-2: stage hi of last tile only
    PH(b, 0, "4", stage(t + 1, 1), stage(t + 1, 3));
    PH(b, 1, "4", (void)0, (void)0);
    ++t;
  }
  {
    const int b = t & 1;  // t == NT-1: nothing left to stage
    PH(b, 0, "2", (void)0, (void)0);
    PH(b, 1, "0", (void)0, (void)0);
  }

  // ---- epilogue: C/D layout col=lane&15, row=kl*4+reg
  const int m0 = wr * 64 + kl * 4;
  const int n0 = wc * 64 + r4;
  if (MODE == 0) {
    short* D = (short*)Dp;
#pragma unroll
    for (int mi = 0; mi < 4; ++mi)
#pragma unroll
      for (int ni = 0; ni < 4; ++ni)
#pragma unroll
        for (int r = 0; r < 4; ++r) {
          int row = bm * 256 + m0 + mi * 16 + r;
          int col = bn * 256 + n0 + ni * 16;
          D[(size_t)row * ldd + col] = f2bf(acc[mi][ni][r]);
        }
  } else {
    float* D = (float*)Dp + (size_t)((bn * 256) >> 14) * 8388608;
#pragma unroll
    for (int mi = 0; mi < 4; ++mi)
#pragma unroll
      for (int ni = 0; ni < 4; ++ni)
#pragma unroll
        for (int r = 0; r < 4; ++r) {
          int c = bm * 256 + m0 + mi * 16 + r;          // channel (M dim)
          int n = (bn * 256 + n0 + ni * 16) & 16383;    // spatial within batch
          D[(size_t)c * 16384 + n] = acc[mi][ni][r] + bsum[c];
        }
  }
}

// ---------- MFMA axial attention: one WAVE per (sequence, head) ----------
// (round-10/11 proven) qkv [n][1536] bf16; o [n][1536] bf16 at column obase.
template <int L>
__global__ __launch_bounds__(256) void attn_mfma_k(const short* __restrict__ qkv,
                                                   short* __restrict__ o, int Adiv,
                                                   int Bmul, int Cmul, int stride,
                                                   int obase) {
  constexpr int MT = L / 16;            // 2 or 1 row tiles
  constexpr int PITCH = 40;             // shorts; 80B rows
  __shared__ short lds[4 * (32 + 64) * PITCH];
  const int tid = threadIdx.x;
  const int lane = tid & 63, wave = tid >> 6;
  short* p_lds = lds + wave * (96 * PITCH);
  short* vt = p_lds + 32 * PITCH;

  const int wid = blockIdx.x * 4 + wave;
  const int s = wid >> 3, head = wid & 7;
  const int base = (s / Adiv) * Bmul + (s % Adiv) * Cmul;
  const int r4 = lane & 15, kl = lane >> 4;

  if constexpr (L == 16) {
    for (int i = lane; i < 96 * PITCH; i += 64) p_lds[i] = 0;
  }

  bf16x8 qf[MT][2], kf[MT][2];
#pragma unroll
  for (int mi = 0; mi < MT; ++mi)
#pragma unroll
    for (int ks = 0; ks < 2; ++ks) {
      size_t nrow = (size_t)(base + (mi * 16 + r4) * stride) * 1536 + head * 64 +
                    ks * 32 + kl * 8;
      qf[mi][ks] = *(const bf16x8*)&qkv[nrow];
      kf[mi][ks] = *(const bf16x8*)&qkv[nrow + 512];
    }

#pragma unroll
  for (int it = 0; it < L / 8; ++it) {
    int j = (lane >> 3) + it * 8;
    uint4 u = *(const uint4*)&qkv[(size_t)(base + j * stride) * 1536 + 1024 +
                                  head * 64 + (lane & 7) * 8];
    ushort e[8];
    *(uint4*)e = u;
#pragma unroll
    for (int q = 0; q < 8; ++q) vt[((lane & 7) * 8 + q) * PITCH + j] = (short)e[q];
  }

  f32x4 sacc[MT][MT];
#pragma unroll
  for (int i = 0; i < MT; ++i)
#pragma unroll
    for (int j = 0; j < MT; ++j) sacc[i][j] = (f32x4){0.f, 0.f, 0.f, 0.f};
#pragma unroll
  for (int mi = 0; mi < MT; ++mi)
#pragma unroll
    for (int ni = 0; ni < MT; ++ni)
#pragma unroll
      for (int ks = 0; ks < 2; ++ks)
        sacc[mi][ni] = __builtin_amdgcn_mfma_f32_16x16x32_bf16(
            qf[mi][ks], kf[ni][ks], sacc[mi][ni], 0, 0, 0);

#pragma unroll
  for (int mi = 0; mi < MT; ++mi) {
    float mx[4], sm[4];
#pragma unroll
    for (int r = 0; r < 4; ++r) {
      float m = sacc[mi][0][r];
      if (MT == 2) m = fmaxf(m, sacc[mi][1][r]);
#pragma unroll
      for (int d = 1; d < 16; d <<= 1) m = fmaxf(m, __shfl_xor(m, d));
      mx[r] = m;
    }
#pragma unroll
    for (int ni = 0; ni < MT; ++ni)
#pragma unroll
      for (int r = 0; r < 4; ++r)
        sacc[mi][ni][r] = __expf((sacc[mi][ni][r] - mx[r]) * 0.125f);
#pragma unroll
    for (int r = 0; r < 4; ++r) {
      float t = sacc[mi][0][r];
      if (MT == 2) t += sacc[mi][1][r];
#pragma unroll
      for (int d = 1; d < 16; d <<= 1) t += __shfl_xor(t, d);
      sm[r] = 1.0f / t;
    }
#pragma unroll
    for (int ni = 0; ni < MT; ++ni)
#pragma unroll
      for (int r = 0; r < 4; ++r)
        p_lds[(mi * 16 + kl * 4 + r) * PITCH + ni * 16 + r4] =
            f2bf(sacc[mi][ni][r] * sm[r]);
  }
  asm volatile("s_waitcnt lgkmcnt(0)" ::: "memory");

  bf16x8 paf[MT], vbf[4];
#pragma unroll
  for (int mi = 0; mi < MT; ++mi)
    paf[mi] = *(const bf16x8*)&p_lds[(mi * 16 + r4) * PITCH + kl * 8];
#pragma unroll
  for (int nd = 0; nd < 4; ++nd)
    vbf[nd] = *(const bf16x8*)&vt[(nd * 16 + r4) * PITCH + kl * 8];
  f32x4 oacc[MT][4];
#pragma unroll
  for (int i = 0; i < MT; ++i)
#pragma unroll
    for (int j = 0; j < 4; ++j) oacc[i][j] = (f32x4){0.f, 0.f, 0.f, 0.f};
#pragma unroll
  for (int mi = 0; mi < MT; ++mi)
#pragma unroll
    for (int nd = 0; nd < 4; ++nd)
      oacc[mi][nd] = __builtin_amdgcn_mfma_f32_16x16x32_bf16(paf[mi], vbf[nd],
                                                             oacc[mi][nd], 0, 0, 0);

#pragma unroll
  for (int mi = 0; mi < MT; ++mi)
#pragma unroll
    for (int r = 0; r < 4; ++r) {
      int n = base + (mi * 16 + kl * 4 + r) * stride;
      size_t ob = (size_t)n * 1536 + obase + head * 64 + r4;
#pragma unroll
      for (int nd = 0; nd < 4; ++nd) o[ob + nd * 16] = f2bf(oacc[mi][nd][r]);
    }
}

// ---------- launch ----------
extern "C" void kernel_launch(void* const* d_in, const int* in_sizes, int n_in,
                              void* d_out, int out_size, void* d_ws, size_t ws_size,
                              hipStream_t stream) {
  const float* x = (const float*)d_in[0];
  const float* wq[3];
  const float* wk[3];
  const float* wv[3];
  const float* fc[3];
  const float* fb[3];
  for (int a = 0; a < 3; a++) {
    wq[a] = (const float*)d_in[1 + a * 5];
    wk[a] = (const float*)d_in[2 + a * 5];
    wv[a] = (const float*)d_in[3 + a * 5];
    fc[a] = (const float*)d_in[4 + a * 5];
    fb[a] = (const float*)d_in[5 + a * 5];
  }
  char* ws = (char*)d_ws;
  short* xb = (short*)(ws);                      //  67,108,864 B
  short* qkv = (short*)(ws + 67108864);          // 201,326,592 B
  short* wqkvt = (short*)(ws + 268435456);       //   4,718,592 B (3 x 1536x512)
  short* fctA = (short*)(ws + 273154048);        //   1,572,864 B (512 x 1536)
  float* bsum = (float*)(ws + 274726912);        //       2,048 B
  short* ob = (short*)(ws + 274728960);          // 201,326,592 B (65536 x 1536)
  float* out = (float*)d_out;

  // allow 128 KiB dynamic LDS (host-side, capture-safe)
  (void)hipFuncSetAttribute((const void*)&gemm256_k<0>,
                            hipFuncAttributeMaxDynamicSharedMemorySize, 131072);
  (void)hipFuncSetAttribute((const void*)&gemm256_k<1>,
                            hipFuncAttributeMaxDynamicSharedMemorySize, 131072);

  WPtrs P;
  for (int a = 0; a < 3; a++) {
    P.src[a * 4 + 0] = wq[a];
    P.src[a * 4 + 1] = wk[a];
    P.src[a * 4 + 2] = wv[a];
    P.src[a * 4 + 3] = fc[a];
    P.dst[a * 4 + 0] = wqkvt + (size_t)a * 1536 * 512;
    P.dst[a * 4 + 1] = wqkvt + (size_t)a * 1536 * 512 + 512 * 512;
    P.dst[a * 4 + 2] = wqkvt + (size_t)a * 1536 * 512 + 2 * 512 * 512;
    P.dst[a * 4 + 3] = fctA + a * 512;   // packed [c][a*512 + k], ld 1536
    P.ld[a * 4 + 0] = 512;
    P.ld[a * 4 + 1] = 512;
    P.ld[a * 4 + 2] = 512;
    P.ld[a * 4 + 3] = 1536;
  }
  transpose_w_k<<<dim3(8, 8, 12), 256, 0, stream>>>(P);
  bsum_k<<<dim3(2), 256, 0, stream>>>(fb[0], fb[1], fb[2], bsum);
  transpose_x_k<<<dim3(256, 8, 4), 256, 0, stream>>>(x, xb);

  // per-axis attention geometry: base = (s/Adiv)*Bmul + (s%Adiv)*Cmul, rows step `stride`
  const int Ad[3] = {1, 32, 1024};
  const int Bm_[3] = {32, 1024, 16384};
  const int Cm[3] = {0, 1, 1};
  const int St[3] = {1, 32, 1024};
  const int Ls[3] = {32, 32, 16};

  for (int a = 0; a < 3; a++) {
    // QKV: M=65536 (256 bm tiles), N=1536 (6 bn tiles), K=512 (NT=8)
    gemm256_k<0><<<dim3(1536), 1024, 131072, stream>>>(
        xb, 512, wqkvt + (size_t)a * 1536 * 512, 512, (void*)qkv, 512, 1536,
        nullptr, 6);
    if (Ls[a] == 32)
      attn_mfma_k<32><<<dim3(4096), 256, 0, stream>>>(qkv, ob, Ad[a], Bm_[a], Cm[a],
                                                      St[a], a * 512);
    else
      attn_mfma_k<16><<<dim3(8192), 256, 0, stream>>>(qkv, ob, Ad[a], Bm_[a], Cm[a],
                                                      St[a], a * 512);
  }
  // fused fc: out[c][n] = sum_a ob_all[n][a*512+k] * fctA[c][a*512+k] + bsum[c]
  // M=512 (2 bm), N=65536 (256 bn), K=1536 (NT=24), single write, no RMW
  gemm256_k<1><<<dim3(512), 1024, 131072, stream>>>(
      fctA, 1536, ob, 1536, (void*)out, 1536, 0, bsum, 0);
}

// Round 13
// 689.914 us; speedup vs baseline: 1.0665x; 1.0665x over previous
//
#include <hip/hip_runtime.h>
#include <stdint.h>

// ---------- types / helpers ----------
typedef __attribute__((ext_vector_type(8))) short bf16x8;   // 8 bf16 in 4 VGPRs
typedef __attribute__((ext_vector_type(4))) float f32x4;

static __device__ __forceinline__ short f2bf(float f) {
  uint32_t u = __builtin_bit_cast(uint32_t, f);
  u += 0x7fffu + ((u >> 16) & 1u);          // round-to-nearest-even
  return (short)(u >> 16);
}

static __device__ __forceinline__ void gload_lds16(const void* g, void* l) {
  __builtin_amdgcn_global_load_lds((const __attribute__((address_space(1))) void*)g,
                                   (__attribute__((address_space(3))) void*)l, 16, 0, 0);
}

#define GFENCE asm volatile("" ::: "memory")

// ---------- x transpose: (B,C,T,H,W) f32 -> xb[n][c] bf16, n = b*16384 + p ----------
__global__ __launch_bounds__(256) void transpose_x_k(const float* __restrict__ x,
                                                     short* __restrict__ xb) {
  __shared__ float t[64][65];
  const int pt = blockIdx.x, ct = blockIdx.y, b = blockIdx.z;
  const int tid = threadIdx.x;
#pragma unroll
  for (int i = 0; i < 16; i++) {
    int cc = i * 4 + (tid >> 6);
    int pp = tid & 63;
    t[cc][pp] = x[(size_t)(b * 512 + ct * 64 + cc) * 16384 + pt * 64 + pp];
  }
  __syncthreads();
#pragma unroll
  for (int i = 0; i < 2; i++) {
    int seg = i * 256 + tid;
    int pw = seg >> 3, c8 = seg & 7;
    short tmp[8];
#pragma unroll
    for (int k = 0; k < 8; k++) tmp[k] = f2bf(t[c8 * 8 + k][pw]);
    *(uint4*)&xb[(size_t)(b * 16384 + pt * 64 + pw) * 512 + ct * 64 + c8 * 8] =
        *(const uint4*)tmp;
  }
}

// ---------- weight transpose: 12x (512x512 f32 [k][n]) -> bf16 [n][k], per-dst ld ----------
struct WPtrs {
  const float* src[12];
  short* dst[12];
  int ld[12];
};

__global__ __launch_bounds__(256) void transpose_w_k(WPtrs P) {
  __shared__ float t[64][65];
  const int kt = blockIdx.x, nt = blockIdx.y, z = blockIdx.z;
  const float* src = P.src[z];
  short* dst = P.dst[z];
  const int ld = P.ld[z];
  const int tid = threadIdx.x;
#pragma unroll
  for (int i = 0; i < 16; i++) {
    int kk = i * 4 + (tid >> 6);
    int nn = tid & 63;
    t[kk][nn] = src[(kt * 64 + kk) * 512 + nt * 64 + nn];
  }
  __syncthreads();
#pragma unroll
  for (int i = 0; i < 2; i++) {
    int seg = i * 256 + tid;
    int nn = seg >> 3, k8 = seg & 7;
    short tmp[8];
#pragma unroll
    for (int k = 0; k < 8; k++) tmp[k] = f2bf(t[k8 * 8 + k][nn]);
    *(uint4*)&dst[(size_t)(nt * 64 + nn) * ld + kt * 64 + k8 * 8] = *(const uint4*)tmp;
  }
}

__global__ void bsum_k(const float* a, const float* b, const float* c, float* o) {
  int i = blockIdx.x * 256 + threadIdx.x;
  if (i < 512) o[i] = a[i] + b[i] + c[i];
}

// ---------- 256x256 read-ahead 8-phase GEMM: D = A(MxK,lda)*B(NxK,ldb)^T ----------
// Round-11 structure with the CORRECTED bank swizzle (round-6-proven involution):
//   read kls = kl ^ ((r4>>1)&3); stage schk = (tid&3) ^ ((tid>>3)&3).
//   -> 2 lanes per 4-bank span per 16-lane group, 8 lanes/span per wave = the
//   8-cycle service floor, 0 conflicts (verified 0 in rounds 6/7 at 128-tile).
// Phase slot = [vmcnt?][barrier][reads p+1][stage][MFMA p]; ping-pong frag regs.
// vmcnt ledger: steady vmcnt(6) @P1/@P3; prologue 8; tail (NT-2): 6/4; (NT-1): 0/0.
// MODE 0: D bf16 [M][ldd].  MODE 1: D f32 out (B,C,THW) = v + bsum[c].
#define READ_B(DST, b, kh)                                                     \
  do {                                                                         \
    _Pragma("unroll") for (int ni = 0; ni < 4; ++ni) DST[ni] =                 \
        *(const bf16x8*)(smem + ((b) * 4 + 2 + (kh)) * 16384 + boff +          \
                         ni * 1024);                                           \
  } while (0)

#define READ_A(DST, b, kh, mq)                                                 \
  do {                                                                         \
    _Pragma("unroll") for (int mi = 0; mi < 4; ++mi) DST[mi] =                 \
        *(const bf16x8*)(smem + ((b) * 4 + (kh)) * 16384 + aoff +              \
                         ((mq) * 4 + mi) * 1024);                              \
  } while (0)

#define MFMAX(mq, AF, BF)                                                      \
  do {                                                                         \
    __builtin_amdgcn_s_setprio(1);                                             \
    _Pragma("unroll") for (int mi = 0; mi < 4; ++mi)                           \
        _Pragma("unroll") for (int ni = 0; ni < 4; ++ni) acc[(mq) * 4 + mi]    \
            [ni] = __builtin_amdgcn_mfma_f32_16x16x32_bf16(                    \
                AF[mi], BF[ni], acc[(mq) * 4 + mi][ni], 0, 0, 0);              \
    __builtin_amdgcn_s_setprio(0);                                             \
    GFENCE;                                                                    \
  } while (0)

#define TILE_RA(b, b2, W1, W3, S0, S1, S2, S3, RA)                             \
  do {                                                                         \
    /* P0: mfma(kh0,mq0) on afA,bfA; read A(kh0,mq1) */                        \
    __builtin_amdgcn_s_barrier();                                              \
    GFENCE;                                                                    \
    READ_A(afB, b, 0, 1);                                                      \
    S0;                                                                        \
    GFENCE;                                                                    \
    MFMAX(0, afA, bfA);                                                        \
    /* P1: mfma(kh0,mq1) on afB,bfA; read B(kh1)+A(kh1,mq0) */                 \
    asm volatile("s_waitcnt vmcnt(" W1 ")" ::: "memory");                      \
    __builtin_amdgcn_s_barrier();                                              \
    GFENCE;                                                                    \
    READ_B(bfB, b, 1);                                                         \
    READ_A(afA, b, 1, 0);                                                      \
    S1;                                                                        \
    GFENCE;                                                                    \
    MFMAX(1, afB, bfA);                                                        \
    /* P2: mfma(kh1,mq0) on afA,bfB; read A(kh1,mq1) */                        \
    __builtin_amdgcn_s_barrier();                                              \
    GFENCE;                                                                    \
    READ_A(afB, b, 1, 1);                                                      \
    S2;                                                                        \
    GFENCE;                                                                    \
    MFMAX(0, afA, bfB);                                                        \
    /* P3: mfma(kh1,mq1) on afB,bfB; read B,A(kh0) of next tile */             \
    asm volatile("s_waitcnt vmcnt(" W3 ")" ::: "memory");                      \
    __builtin_amdgcn_s_barrier();                                              \
    GFENCE;                                                                    \
    RA;                                                                        \
    S3;                                                                        \
    GFENCE;                                                                    \
    MFMAX(1, afB, bfB);                                                        \
  } while (0)

template <int MODE>
__global__ __launch_bounds__(512, 2) void gemm256_k(const short* __restrict__ A,
                                                    int lda,
                                                    const short* __restrict__ B,
                                                    int ldb, void* __restrict__ Dp,
                                                    int K, int ldd,
                                                    const float* __restrict__ bsum,
                                                    int GN) {
  extern __shared__ char smem[];
  const int tid = threadIdx.x;
  const int lane = tid & 63, wave = tid >> 6;
  const int wr = wave >> 2, wc = wave & 3;
  const int r4 = lane & 15, kl = lane >> 4;

  // bijective XCD swizzle (gridDim.x % 8 == 0 for all our grids)
  int bid = blockIdx.x;
  const int cpx = gridDim.x >> 3;
  bid = (bid & 7) * cpx + (bid >> 3);
  int bm, bn;
  if constexpr (MODE == 0) {
    bn = bid % GN;
    bm = bid / GN;
  } else {
    bm = bid & 1;
    bn = bid >> 1;
  }

  const int NT = K >> 6;

  const int srow = tid >> 2;                       // 0..127 (instr i adds 128)
  const int schk = (tid & 3) ^ ((tid >> 3) & 3);   // CORRECTED involution
  const short* gA0 = A + (size_t)(bm * 256 + srow) * lda + schk * 8;
  const short* gB0 = B + (size_t)(bn * 256 + srow) * ldb + schk * 8;

  auto stage = [&](int tt, int x) {  // x: 0 ALO, 1 AHI, 2 BLO, 3 BHI
    const short* g = (x < 2) ? gA0 : gB0;
    const size_t rstep = (size_t)128 * ((x < 2) ? lda : ldb);
    const size_t koff = (size_t)tt * 64 + (x & 1) * 32;
    char* ldst = smem + (((tt & 1) * 4 + x) * 16384) + wave * 1024;
#pragma unroll
    for (int i = 0; i < 2; ++i)
      gload_lds16(g + i * rstep + koff, ldst + i * 8192);
  };

  const int kls = kl ^ ((r4 >> 1) & 3);            // CORRECTED involution
  const int aoff = wr * 8192 + r4 * 64 + kls * 16;
  const int boff = wc * 4096 + r4 * 64 + kls * 16;

  f32x4 acc[8][4];
#pragma unroll
  for (int i = 0; i < 8; ++i)
#pragma unroll
    for (int j = 0; j < 4; ++j) acc[i][j] = (f32x4){0.f, 0.f, 0.f, 0.f};
  bf16x8 afA[4], afB[4], bfA[4], bfB[4];

  // prologue: ALO0 BLO0 AHI0 BHI0 ALO1 BLO1 (12 loads); retire ALO0,BLO0;
  // then pre-issue tile0 kh0 fragments (consumed by P0(0)).
  stage(0, 0);
  stage(0, 2);
  stage(0, 1);
  stage(0, 3);
  stage(1, 0);
  stage(1, 2);
  asm volatile("s_waitcnt vmcnt(8)" ::: "memory");
  __builtin_amdgcn_s_barrier();
  GFENCE;
  READ_B(bfA, 0, 0);
  READ_A(afA, 0, 0, 0);
  GFENCE;

  int t = 0;
  for (; t < NT - 2; ++t) {
    const int b = t & 1, b2 = b ^ 1;
    TILE_RA(b, b2, "6", "6", stage(t + 1, 1), stage(t + 1, 3), stage(t + 2, 0),
            stage(t + 2, 2), {
              READ_B(bfA, b2, 0);
              READ_A(afA, b2, 0, 0);
            });
  }
  {
    const int b = t & 1, b2 = b ^ 1;  // t == NT-2: hi stages only; RA for last tile
    TILE_RA(b, b2, "6", "4", stage(t + 1, 1), stage(t + 1, 3), (void)0, (void)0, {
      READ_B(bfA, b2, 0);
      READ_A(afA, b2, 0, 0);
    });
    ++t;
  }
  {
    const int b = t & 1, b2 = b ^ 1;  // t == NT-1: no stages, no read-ahead
    TILE_RA(b, b2, "0", "0", (void)0, (void)0, (void)0, (void)0, (void)0);
  }

  // ---- epilogue
  const int m0 = wr * 128 + kl * 4;
  const int n0 = wc * 64 + r4;
  if (MODE == 0) {
    short* D = (short*)Dp;
#pragma unroll
    for (int mi = 0; mi < 8; ++mi)
#pragma unroll
      for (int ni = 0; ni < 4; ++ni)
#pragma unroll
        for (int r = 0; r < 4; ++r) {
          int row = bm * 256 + m0 + mi * 16 + r;
          int col = bn * 256 + n0 + ni * 16;
          D[(size_t)row * ldd + col] = f2bf(acc[mi][ni][r]);
        }
  } else {
    float* D = (float*)Dp + (size_t)((bn * 256) >> 14) * 8388608;
#pragma unroll
    for (int mi = 0; mi < 8; ++mi)
#pragma unroll
      for (int ni = 0; ni < 4; ++ni)
#pragma unroll
        for (int r = 0; r < 4; ++r) {
          int c = bm * 256 + m0 + mi * 16 + r;          // channel (M dim)
          int n = (bn * 256 + n0 + ni * 16) & 16383;    // spatial within batch
          D[(size_t)c * 16384 + n] = acc[mi][ni][r] + bsum[c];
        }
  }
}

// ---------- MFMA axial attention: one WAVE per (sequence, head) ----------
// (round-10/11 proven) qkv [n][1536] bf16; o [n][1536] bf16 at column obase.
template <int L>
__global__ __launch_bounds__(256) void attn_mfma_k(const short* __restrict__ qkv,
                                                   short* __restrict__ o, int Adiv,
                                                   int Bmul, int Cmul, int stride,
                                                   int obase) {
  constexpr int MT = L / 16;            // 2 or 1 row tiles
  constexpr int PITCH = 40;             // shorts; 80B rows
  __shared__ short lds[4 * (32 + 64) * PITCH];
  const int tid = threadIdx.x;
  const int lane = tid & 63, wave = tid >> 6;
  short* p_lds = lds + wave * (96 * PITCH);
  short* vt = p_lds + 32 * PITCH;

  const int wid = blockIdx.x * 4 + wave;
  const int s = wid >> 3, head = wid & 7;
  const int base = (s / Adiv) * Bmul + (s % Adiv) * Cmul;
  const int r4 = lane & 15, kl = lane >> 4;

  if constexpr (L == 16) {
    for (int i = lane; i < 96 * PITCH; i += 64) p_lds[i] = 0;
  }

  bf16x8 qf[MT][2], kf[MT][2];
#pragma unroll
  for (int mi = 0; mi < MT; ++mi)
#pragma unroll
    for (int ks = 0; ks < 2; ++ks) {
      size_t nrow = (size_t)(base + (mi * 16 + r4) * stride) * 1536 + head * 64 +
                    ks * 32 + kl * 8;
      qf[mi][ks] = *(const bf16x8*)&qkv[nrow];
      kf[mi][ks] = *(const bf16x8*)&qkv[nrow + 512];
    }

#pragma unroll
  for (int it = 0; it < L / 8; ++it) {
    int j = (lane >> 3) + it * 8;
    uint4 u = *(const uint4*)&qkv[(size_t)(base + j * stride) * 1536 + 1024 +
                                  head * 64 + (lane & 7) * 8];
    ushort e[8];
    *(uint4*)e = u;
#pragma unroll
    for (int q = 0; q < 8; ++q) vt[((lane & 7) * 8 + q) * PITCH + j] = (short)e[q];
  }

  f32x4 sacc[MT][MT];
#pragma unroll
  for (int i = 0; i < MT; ++i)
#pragma unroll
    for (int j = 0; j < MT; ++j) sacc[i][j] = (f32x4){0.f, 0.f, 0.f, 0.f};
#pragma unroll
  for (int mi = 0; mi < MT; ++mi)
#pragma unroll
    for (int ni = 0; ni < MT; ++ni)
#pragma unroll
      for (int ks = 0; ks < 2; ++ks)
        sacc[mi][ni] = __builtin_amdgcn_mfma_f32_16x16x32_bf16(
            qf[mi][ks], kf[ni][ks], sacc[mi][ni], 0, 0, 0);

#pragma unroll
  for (int mi = 0; mi < MT; ++mi) {
    float mx[4], sm[4];
#pragma unroll
    for (int r = 0; r < 4; ++r) {
      float m = sacc[mi][0][r];
      if (MT == 2) m = fmaxf(m, sacc[mi][1][r]);
#pragma unroll
      for (int d = 1; d < 16; d <<= 1) m = fmaxf(m, __shfl_xor(m, d));
      mx[r] = m;
    }
#pragma unroll
    for (int ni = 0; ni < MT; ++ni)
#pragma unroll
      for (int r = 0; r < 4; ++r)
        sacc[mi][ni][r] = __expf((sacc[mi][ni][r] - mx[r]) * 0.125f);
#pragma unroll
    for (int r = 0; r < 4; ++r) {
      float t = sacc[mi][0][r];
      if (MT == 2) t += sacc[mi][1][r];
#pragma unroll
      for (int d = 1; d < 16; d <<= 1) t += __shfl_xor(t, d);
      sm[r] = 1.0f / t;
    }
#pragma unroll
    for (int ni = 0; ni < MT; ++ni)
#pragma unroll
      for (int r = 0; r < 4; ++r)
        p_lds[(mi * 16 + kl * 4 + r) * PITCH + ni * 16 + r4] =
            f2bf(sacc[mi][ni][r] * sm[r]);
  }
  asm volatile("s_waitcnt lgkmcnt(0)" ::: "memory");

  bf16x8 paf[MT], vbf[4];
#pragma unroll
  for (int mi = 0; mi < MT; ++mi)
    paf[mi] = *(const bf16x8*)&p_lds[(mi * 16 + r4) * PITCH + kl * 8];
#pragma unroll
  for (int nd = 0; nd < 4; ++nd)
    vbf[nd] = *(const bf16x8*)&vt[(nd * 16 + r4) * PITCH + kl * 8];
  f32x4 oacc[MT][4];
#pragma unroll
  for (int i = 0; i < MT; ++i)
#pragma unroll
    for (int j = 0; j < 4; ++j) oacc[i][j] = (f32x4){0.f, 0.f, 0.f, 0.f};
#pragma unroll
  for (int mi = 0; mi < MT; ++mi)
#pragma unroll
    for (int nd = 0; nd < 4; ++nd)
      oacc[mi][nd] = __builtin_amdgcn_mfma_f32_16x16x32_bf16(paf[mi], vbf[nd],
                                                             oacc[mi][nd], 0, 0, 0);

#pragma unroll
  for (int mi = 0; mi < MT; ++mi)
#pragma unroll
    for (int r = 0; r < 4; ++r) {
      int n = base + (mi * 16 + kl * 4 + r) * stride;
      size_t ob = (size_t)n * 1536 + obase + head * 64 + r4;
#pragma unroll
      for (int nd = 0; nd < 4; ++nd) o[ob + nd * 16] = f2bf(oacc[mi][nd][r]);
    }
}

// ---------- launch ----------
extern "C" void kernel_launch(void* const* d_in, const int* in_sizes, int n_in,
                              void* d_out, int out_size, void* d_ws, size_t ws_size,
                              hipStream_t stream) {
  const float* x = (const float*)d_in[0];
  const float* wq[3];
  const float* wk[3];
  const float* wv[3];
  const float* fc[3];
  const float* fb[3];
  for (int a = 0; a < 3; a++) {
    wq[a] = (const float*)d_in[1 + a * 5];
    wk[a] = (const float*)d_in[2 + a * 5];
    wv[a] = (const float*)d_in[3 + a * 5];
    fc[a] = (const float*)d_in[4 + a * 5];
    fb[a] = (const float*)d_in[5 + a * 5];
  }
  char* ws = (char*)d_ws;
  short* xb = (short*)(ws);                      //  67,108,864 B
  short* qkv = (short*)(ws + 67108864);          // 201,326,592 B
  short* wqkvt = (short*)(ws + 268435456);       //   4,718,592 B (3 x 1536x512)
  short* fctA = (short*)(ws + 273154048);        //   1,572,864 B (512 x 1536)
  float* bsum = (float*)(ws + 274726912);        //       2,048 B
  short* ob = (short*)(ws + 274728960);          // 201,326,592 B (65536 x 1536)
  float* out = (float*)d_out;

  // allow 128 KiB dynamic LDS (host-side, capture-safe)
  (void)hipFuncSetAttribute((const void*)&gemm256_k<0>,
                            hipFuncAttributeMaxDynamicSharedMemorySize, 131072);
  (void)hipFuncSetAttribute((const void*)&gemm256_k<1>,
                            hipFuncAttributeMaxDynamicSharedMemorySize, 131072);

  WPtrs P;
  for (int a = 0; a < 3; a++) {
    P.src[a * 4 + 0] = wq[a];
    P.src[a * 4 + 1] = wk[a];
    P.src[a * 4 + 2] = wv[a];
    P.src[a * 4 + 3] = fc[a];
    P.dst[a * 4 + 0] = wqkvt + (size_t)a * 1536 * 512;
    P.dst[a * 4 + 1] = wqkvt + (size_t)a * 1536 * 512 + 512 * 512;
    P.dst[a * 4 + 2] = wqkvt + (size_t)a * 1536 * 512 + 2 * 512 * 512;
    P.dst[a * 4 + 3] = fctA + a * 512;   // packed [c][a*512 + k], ld 1536
    P.ld[a * 4 + 0] = 512;
    P.ld[a * 4 + 1] = 512;
    P.ld[a * 4 + 2] = 512;
    P.ld[a * 4 + 3] = 1536;
  }
  transpose_w_k<<<dim3(8, 8, 12), 256, 0, stream>>>(P);
  bsum_k<<<dim3(2), 256, 0, stream>>>(fb[0], fb[1], fb[2], bsum);
  transpose_x_k<<<dim3(256, 8, 4), 256, 0, stream>>>(x, xb);

  // per-axis attention geometry: base = (s/Adiv)*Bmul + (s%Adiv)*Cmul, rows step `stride`
  const int Ad[3] = {1, 32, 1024};
  const int Bm_[3] = {32, 1024, 16384};
  const int Cm[3] = {0, 1, 1};
  const int St[3] = {1, 32, 1024};
  const int Ls[3] = {32, 32, 16};

  for (int a = 0; a < 3; a++) {
    // QKV: M=65536 (256 bm tiles), N=1536 (6 bn tiles), K=512 (NT=8)
    gemm256_k<0><<<dim3(1536), 512, 131072, stream>>>(
        xb, 512, wqkvt + (size_t)a * 1536 * 512, 512, (void*)qkv, 512, 1536,
        nullptr, 6);
    if (Ls[a] == 32)
      attn_mfma_k<32><<<dim3(4096), 256, 0, stream>>>(qkv, ob, Ad[a], Bm_[a], Cm[a],
                                                      St[a], a * 512);
    else
      attn_mfma_k<16><<<dim3(8192), 256, 0, stream>>>(qkv, ob, Ad[a], Bm_[a], Cm[a],
                                                      St[a], a * 512);
  }
  // fused fc: out[c][n] = sum_a ob_all[n][a*512+k] * fctA[c][a*512+k] + bsum[c]
  // M=512 (2 bm), N=65536 (256 bn), K=1536 (NT=24), single write, no RMW
  gemm256_k<1><<<dim3(512), 512, 131072, stream>>>(
      fctA, 1536, ob, 1536, (void*)out, 1536, 0, bsum, 0);
}